// Round 12
// baseline (912.336 us; speedup 1.0000x reference)
//
#include <hip/hip_runtime.h>
#include <hip/hip_fp16.h>

// PathGCN fused layer — fp32 math, f16 gather operand, SORTED gather order.
// out[n,j] = relu( sum_k res[n,k] * fcw[j,k] )
// res[n,k] = (1/8) * sum_{p,l} pw[l,k] * feats[paths[p,n,l], k]
//
// R12: the only lever is bytes. Law from R4..R11: time = (FETCH+WRITE)/~3.4TB/s
// regardless of occupancy/barriers/ILP/issue-count (R11: VALU 62->31% yet same
// byte-rate). FETCH=691MB is 42% of the 1.64GB logical gather stream (per-XCD
// L2 4MB vs 25.6MB f16 feats, random order). Sum order is free: sort each
// node's 64 (idx,l) pairs by idx (bitonic in LDS, key=idx*8+l) so co-resident
// blocks sweep the index space in near-lockstep -> instantaneous band ~3-5MB
// ~ per-XCD L2 -> L2 hit rate up, FETCH down. Accumulate = fma with pw[l]
// (LDS) per gather — same VALU count as add-then-fma. Phase 2 rebuilt with
// o[8] + constant indices (R11's pointer-select forced scratch: WRITE 256MB).

#define N_NODES 100000
#define HIDDEN  128
#define NPATH   8
#define PLEN    8
#define NPB     16     // nodes per block (256 threads = 16 nodes x 16 lanes)
#define KT      32     // k-tile width for fcw staging

// ---------------- Kernel 0: feats f32 -> f16 copy (workspace) ----------------
__global__ void PathGCNLayer_61306363183203_tohalf(
    const float4* __restrict__ feats4,   // (N*32) float4
    uint2*        __restrict__ fh)       // (N*32) uint2 = 4 halfs
{
    const size_t i = (size_t)blockIdx.x * blockDim.x + threadIdx.x;
    if (i < (size_t)N_NODES * 32) {
        const float4 v = feats4[i];
        __half2 a = __floats2half2_rn(v.x, v.y);
        __half2 b = __floats2half2_rn(v.z, v.w);
        uint2 o;
        o.x = *reinterpret_cast<unsigned int*>(&a);
        o.y = *reinterpret_cast<unsigned int*>(&b);
        fh[i] = o;
    }
}

// ------ Kernel 1: fused sorted-gather(f16,16B/lane) + einsum + GEMM + ReLU ------
__global__ void PathGCNLayer_61306363183203_fused_hs(
    const uint4*  __restrict__ feats_h4, // (N, 16) rows of uint4 (8 halfs)
    const int*    __restrict__ paths,    // (8, N, 8) int32
    const float4* __restrict__ pw4,      // (8, 32) float4 rows
    const float4* __restrict__ fcw4,     // (128, 32) float4 rows
    float*        __restrict__ out)      // (N, 128) f32
{
    __shared__ unsigned skey[NPB][64];           // (idx<<3)|l per node (4 KB)
    __shared__ float4   sres4[NPB][33];          // res tile (8.4 KB)
    __shared__ float    fcwt[HIDDEN][KT + 1];    // fcw k-tile, pad 33 (16.9 KB)
    __shared__ float4   spw4[NPATH * 32];        // pw rows as float4 (4 KB)

    const int tid  = threadIdx.x;
    const int n0   = blockIdx.x * NPB;
    const int node = tid >> 4;      // 0..15
    const int c    = tid & 15;      // uint4 column within row (16 B granule)

    // ---- stage pw (256 float4s) and build sort keys ----
    spw4[tid] = pw4[tid];
    {
        const int p  = tid >> 5;    // 0..7
        const int i0 = tid & 31;
        const size_t base = (size_t)p * (N_NODES * PLEN) + (size_t)n0 * PLEN;
        #pragma unroll
        for (int q = 0; q < 4; ++q) {
            const int i = i0 + 32 * q;                 // 0..127 = node*8 + l
            const unsigned idx = (unsigned)paths[base + i];
            skey[i >> 3][p * 8 + (i & 7)] = (idx << 3) | (unsigned)(i & 7);
        }
    }
    __syncthreads();

    // ---- bitonic sort of 64 keys per node (16 lanes cooperate) ----
    for (int kk = 2; kk <= 64; kk <<= 1) {
        for (int j = kk >> 1; j > 0; j >>= 1) {
            #pragma unroll
            for (int q = 0; q < 4; ++q) {
                const int i = c + 16 * q;
                const int partner = i ^ j;
                if (partner > i) {
                    const unsigned a = skey[node][i];
                    const unsigned b = skey[node][partner];
                    const bool asc = (i & kk) == 0;
                    if ((a > b) == asc) {
                        skey[node][i]       = b;
                        skey[node][partner] = a;
                    }
                }
            }
            __syncthreads();
        }
    }

    // ---- phase 1: sorted 8-deep gather batches, fma with pw[l] ----
    float a0 = 0.f, a1 = 0.f, a2 = 0.f, a3 = 0.f,
          a4 = 0.f, a5 = 0.f, a6 = 0.f, a7 = 0.f;
    #pragma unroll
    for (int g = 0; g < 64; g += 8) {
        const unsigned k0_ = skey[node][g + 0];   // same addr across node's
        const unsigned k1_ = skey[node][g + 1];   // 16 lanes -> LDS broadcast
        const unsigned k2_ = skey[node][g + 2];
        const unsigned k3_ = skey[node][g + 3];
        const unsigned k4_ = skey[node][g + 4];
        const unsigned k5_ = skey[node][g + 5];
        const unsigned k6_ = skey[node][g + 6];
        const unsigned k7_ = skey[node][g + 7];
        uint4 hv0 = feats_h4[(size_t)(k0_ >> 3) * 16 + c];
        uint4 hv1 = feats_h4[(size_t)(k1_ >> 3) * 16 + c];
        uint4 hv2 = feats_h4[(size_t)(k2_ >> 3) * 16 + c];
        uint4 hv3 = feats_h4[(size_t)(k3_ >> 3) * 16 + c];
        uint4 hv4 = feats_h4[(size_t)(k4_ >> 3) * 16 + c];
        uint4 hv5 = feats_h4[(size_t)(k5_ >> 3) * 16 + c];
        uint4 hv6 = feats_h4[(size_t)(k6_ >> 3) * 16 + c];
        uint4 hv7 = feats_h4[(size_t)(k7_ >> 3) * 16 + c];
        #define ACCW(hv, key)                                                           \
        {                                                                               \
            const int l = (int)((key) & 7u);                                            \
            const float4 w0 = spw4[l * 32 + 2 * c];                                     \
            const float4 w1 = spw4[l * 32 + 2 * c + 1];                                 \
            const float2 f0 = __half22float2(*reinterpret_cast<const __half2*>(&hv.x)); \
            const float2 f1 = __half22float2(*reinterpret_cast<const __half2*>(&hv.y)); \
            const float2 f2 = __half22float2(*reinterpret_cast<const __half2*>(&hv.z)); \
            const float2 f3 = __half22float2(*reinterpret_cast<const __half2*>(&hv.w)); \
            a0 = fmaf(f0.x, w0.x, a0); a1 = fmaf(f0.y, w0.y, a1);                       \
            a2 = fmaf(f1.x, w0.z, a2); a3 = fmaf(f1.y, w0.w, a3);                       \
            a4 = fmaf(f2.x, w1.x, a4); a5 = fmaf(f2.y, w1.y, a5);                       \
            a6 = fmaf(f3.x, w1.z, a6); a7 = fmaf(f3.y, w1.w, a7);                       \
        }
        ACCW(hv0, k0_) ACCW(hv1, k1_) ACCW(hv2, k2_) ACCW(hv3, k3_)
        ACCW(hv4, k4_) ACCW(hv5, k5_) ACCW(hv6, k6_) ACCW(hv7, k7_)
        #undef ACCW
    }
    {
        float4 r0, r1;
        r0.x = a0 * 0.125f; r0.y = a1 * 0.125f; r0.z = a2 * 0.125f; r0.w = a3 * 0.125f;
        r1.x = a4 * 0.125f; r1.y = a5 * 0.125f; r1.z = a6 * 0.125f; r1.w = a7 * 0.125f;
        sres4[node][2 * c]     = r0;
        sres4[node][2 * c + 1] = r1;
    }

    // ---- phase 2: out[node][j], j = c + 16*jj, register array o[8] ----
    float o[8] = {0.f, 0.f, 0.f, 0.f, 0.f, 0.f, 0.f, 0.f};

    #pragma unroll
    for (int kt = 0; kt < HIDDEN / KT; ++kt) {
        __syncthreads();   // protect fcwt reuse (and sres on first iter)
        {
            const int j    = tid >> 1;        // 0..127
            const int half = tid & 1;         // 0..1
            const int gbase = j * 32 + kt * (KT / 4) + half * 4;
            const int lbase = half * 16;
            #pragma unroll
            for (int q = 0; q < 4; ++q) {
                const float4 v = fcw4[gbase + q];
                fcwt[j][lbase + q * 4 + 0] = v.x;
                fcwt[j][lbase + q * 4 + 1] = v.y;
                fcwt[j][lbase + q * 4 + 2] = v.z;
                fcwt[j][lbase + q * 4 + 3] = v.w;
            }
        }
        __syncthreads();

        #pragma unroll
        for (int kc = 0; kc < KT / 4; ++kc) {
            const float4 rv = sres4[node][kt * (KT / 4) + kc];  // 16-lane broadcast
            const int k0 = kc * 4;
            #pragma unroll
            for (int jj = 0; jj < 8; ++jj) {
                const int j = c + 16 * jj;
                o[jj] = fmaf(rv.x, fcwt[j][k0    ], o[jj]);
                o[jj] = fmaf(rv.y, fcwt[j][k0 + 1], o[jj]);
                o[jj] = fmaf(rv.z, fcwt[j][k0 + 2], o[jj]);
                o[jj] = fmaf(rv.w, fcwt[j][k0 + 3], o[jj]);
            }
        }
    }

    // ReLU + store: per jj, 16 consecutive floats per node (64B runs)
    {
        const size_t obase = (size_t)(n0 + node) * HIDDEN + c;
        #pragma unroll
        for (int jj = 0; jj < 8; ++jj) {
            const float v = o[jj] > 0.f ? o[jj] : 0.f;
            out[obase + 16 * jj] = v;
        }
    }
}

// ---------------- Fallback: R0's fused f32 kernel (proven, no ws needed) ----------------
__global__ void PathGCNLayer_61306363183203_fused(
    const float4* __restrict__ feats4,
    const int*    __restrict__ paths,
    const float4* __restrict__ pw4,
    const float4* __restrict__ fcw4,
    float*        __restrict__ out)
{
    __shared__ int    sidx[NPATH * 8 * PLEN];
    __shared__ float4 sres4[8][33];
    __shared__ float  fcwt[HIDDEN][KT + 1];

    const int tid  = threadIdx.x;
    const int n0   = blockIdx.x * 8;
    const int node = tid >> 5;
    const int c    = tid & 31;

    {
        const int p = tid >> 5;
        const int i = tid & 31;
        const size_t base = (size_t)p * (N_NODES * PLEN) + (size_t)n0 * PLEN;
        sidx[p * 64 + i]      = paths[base + i];
        sidx[p * 64 + i + 32] = paths[base + i + 32];
    }
    __syncthreads();

    float ax = 0.0f, ay = 0.0f, az = 0.0f, aw = 0.0f;
    #pragma unroll
    for (int l = 0; l < PLEN; ++l) {
        float sx = 0.0f, sy = 0.0f, sz = 0.0f, sw = 0.0f;
        #pragma unroll
        for (int p = 0; p < NPATH; ++p) {
            const int idx = sidx[p * 64 + node * PLEN + l];
            const float4 v = feats4[(size_t)idx * 32 + c];
            sx += v.x; sy += v.y; sz += v.z; sw += v.w;
        }
        const float4 w = pw4[l * 32 + c];
        ax = fmaf(sx, w.x, ax);
        ay = fmaf(sy, w.y, ay);
        az = fmaf(sz, w.z, az);
        aw = fmaf(sw, w.w, aw);
    }
    {
        float4 r;
        r.x = ax * 0.125f; r.y = ay * 0.125f;
        r.z = az * 0.125f; r.w = aw * 0.125f;
        sres4[node][c] = r;
    }

    float o0 = 0.0f, o1 = 0.0f, o2 = 0.0f, o3 = 0.0f;
    #pragma unroll
    for (int kt = 0; kt < HIDDEN / KT; ++kt) {
        __syncthreads();
        {
            const int j    = tid >> 1;
            const int half = tid & 1;
            const int gbase = j * 32 + kt * (KT / 4) + half * 4;
            const int lbase = half * 16;
            #pragma unroll
            for (int q = 0; q < 4; ++q) {
                const float4 v = fcw4[gbase + q];
                fcwt[j][lbase + q * 4 + 0] = v.x;
                fcwt[j][lbase + q * 4 + 1] = v.y;
                fcwt[j][lbase + q * 4 + 2] = v.z;
                fcwt[j][lbase + q * 4 + 3] = v.w;
            }
        }
        __syncthreads();
        #pragma unroll
        for (int kc = 0; kc < KT / 4; ++kc) {
            const float4 rv = sres4[node][kt * (KT / 4) + kc];
            const int k0 = kc * 4;
            o0 = fmaf(rv.x, fcwt[c      ][k0    ], o0);
            o1 = fmaf(rv.x, fcwt[c + 32 ][k0    ], o1);
            o2 = fmaf(rv.x, fcwt[c + 64 ][k0    ], o2);
            o3 = fmaf(rv.x, fcwt[c + 96 ][k0    ], o3);
            o0 = fmaf(rv.y, fcwt[c      ][k0 + 1], o0);
            o1 = fmaf(rv.y, fcwt[c + 32 ][k0 + 1], o1);
            o2 = fmaf(rv.y, fcwt[c + 64 ][k0 + 1], o2);
            o3 = fmaf(rv.y, fcwt[c + 96 ][k0 + 1], o3);
            o0 = fmaf(rv.z, fcwt[c      ][k0 + 2], o0);
            o1 = fmaf(rv.z, fcwt[c + 32 ][k0 + 2], o1);
            o2 = fmaf(rv.z, fcwt[c + 64 ][k0 + 2], o2);
            o3 = fmaf(rv.z, fcwt[c + 96 ][k0 + 2], o3);
            o0 = fmaf(rv.w, fcwt[c      ][k0 + 3], o0);
            o1 = fmaf(rv.w, fcwt[c + 32 ][k0 + 3], o1);
            o2 = fmaf(rv.w, fcwt[c + 64 ][k0 + 3], o2);
            o3 = fmaf(rv.w, fcwt[c + 96 ][k0 + 3], o3);
        }
    }
    {
        const size_t obase = (size_t)(n0 + node) * HIDDEN + c;
        out[obase]      = o0 > 0.0f ? o0 : 0.0f;
        out[obase + 32] = o1 > 0.0f ? o1 : 0.0f;
        out[obase + 64] = o2 > 0.0f ? o2 : 0.0f;
        out[obase + 96] = o3 > 0.0f ? o3 : 0.0f;
    }
}

extern "C" void kernel_launch(void* const* d_in, const int* in_sizes, int n_in,
                              void* d_out, int out_size, void* d_ws, size_t ws_size,
                              hipStream_t stream) {
    const float4* feats4 = (const float4*)d_in[0];  // (N,128) f32
    const int*    paths  = (const int*)d_in[1];     // (8,N,8) int32
    // d_in[2] = init_feats — unused by the reference
    const float4* pw4    = (const float4*)d_in[3];  // (1,8,128) f32
    const float4* fcw4   = (const float4*)d_in[4];  // (128,128) f32
    float* out = (float*)d_out;
    (void)in_sizes; (void)n_in; (void)out_size;

    const size_t half_bytes = (size_t)N_NODES * HIDDEN * sizeof(unsigned short); // 25.6 MB
    if (d_ws != nullptr && ws_size >= half_bytes) {
        uint2* fh = (uint2*)d_ws;
        const int cvt_blocks = (N_NODES * 32 + 255) / 256;   // 3.2M float4s
        PathGCNLayer_61306363183203_tohalf<<<cvt_blocks, 256, 0, stream>>>(feats4, fh);
        PathGCNLayer_61306363183203_fused_hs<<<N_NODES / NPB, 256, 0, stream>>>(
            (const uint4*)d_ws, paths, pw4, fcw4, out);
    } else {
        PathGCNLayer_61306363183203_fused<<<N_NODES / 8, 256, 0, stream>>>(
            feats4, paths, pw4, fcw4, out);
    }
}

// Round 14
// 760.220 us; speedup vs baseline: 1.2001x; 1.2001x over previous
//
#include <hip/hip_runtime.h>
#include <hip/hip_fp16.h>

// PathGCN fused layer — fp32 math, f16 gather operand, SORTED gather order.
// out[n,j] = relu( sum_k res[n,k] * fcw[j,k] )
// res[n,k] = (1/8) * sum_{p,l} pw[l,k] * feats[paths[p,n,l], k]
//
// R14 == R13 resubmit (container infra died pre-launch again; R12 — same
// structure, deeper batch — ran and PASSED, so sort/key/numerics are HW-
// validated; R13 only shrinks the batch to R9's proven reg budget).
// R13: R12's sort test was confounded by register spill (WRITE 1.59GB scratch;
// 8x uint4 batch = 32 data VGPRs > the allocator's 64-reg ceiling; R9's 8x
// uint2 = 16 regs was spill-free). Clean re-test with: (1) 4-deep uint4
// batches (16 data regs, R9's budget) + unroll 2; (2) skey [NPB][65] layout
// (bank=(node+i)%32, <=2-way, was 4-way/30.6M cycles); (3) R12's o[8] phase 2
// kept. Gate: WRITE_SIZE==50MB => clean read of the locality hypothesis.
// If FETCH stays ~691MB with no spill => sweeps don't phase-align; revert R9.

#define N_NODES 100000
#define HIDDEN  128
#define NPATH   8
#define PLEN    8
#define NPB     16     // nodes per block (256 threads = 16 nodes x 16 lanes)
#define KT      32     // k-tile width for fcw staging

// ---------------- Kernel 0: feats f32 -> f16 copy (workspace) ----------------
__global__ void PathGCNLayer_61306363183203_tohalf(
    const float4* __restrict__ feats4,   // (N*32) float4
    uint2*        __restrict__ fh)       // (N*32) uint2 = 4 halfs
{
    const size_t i = (size_t)blockIdx.x * blockDim.x + threadIdx.x;
    if (i < (size_t)N_NODES * 32) {
        const float4 v = feats4[i];
        __half2 a = __floats2half2_rn(v.x, v.y);
        __half2 b = __floats2half2_rn(v.z, v.w);
        uint2 o;
        o.x = *reinterpret_cast<unsigned int*>(&a);
        o.y = *reinterpret_cast<unsigned int*>(&b);
        fh[i] = o;
    }
}

// ------ Kernel 1: fused sorted-gather(f16,16B/lane) + einsum + GEMM + ReLU ------
__global__ void PathGCNLayer_61306363183203_fused_hs(
    const uint4*  __restrict__ feats_h4, // (N, 16) rows of uint4 (8 halfs)
    const int*    __restrict__ paths,    // (8, N, 8) int32
    const float4* __restrict__ pw4,      // (8, 32) float4 rows
    const float4* __restrict__ fcw4,     // (128, 32) float4 rows
    float*        __restrict__ out)      // (N, 128) f32
{
    __shared__ unsigned skey[NPB][65];           // (idx<<3)|l, pad-65 (4.2 KB)
    __shared__ float4   sres4[NPB][33];          // res tile (8.4 KB)
    __shared__ float    fcwt[HIDDEN][KT + 1];    // fcw k-tile, pad 33 (16.9 KB)
    __shared__ float4   spw4[NPATH * 32];        // pw rows as float4 (4 KB)

    const int tid  = threadIdx.x;
    const int n0   = blockIdx.x * NPB;
    const int node = tid >> 4;      // 0..15
    const int c    = tid & 15;      // uint4 column within row (16 B granule)

    // ---- stage pw (256 float4s) and build sort keys ----
    spw4[tid] = pw4[tid];
    {
        const int p  = tid >> 5;    // 0..7
        const int i0 = tid & 31;
        const size_t base = (size_t)p * (N_NODES * PLEN) + (size_t)n0 * PLEN;
        #pragma unroll
        for (int q = 0; q < 4; ++q) {
            const int i = i0 + 32 * q;                 // 0..127 = node*8 + l
            const unsigned idx = (unsigned)paths[base + i];
            skey[i >> 3][p * 8 + (i & 7)] = (idx << 3) | (unsigned)(i & 7);
        }
    }
    __syncthreads();

    // ---- bitonic sort of 64 keys per node (16 lanes cooperate) ----
    for (int kk = 2; kk <= 64; kk <<= 1) {
        for (int j = kk >> 1; j > 0; j >>= 1) {
            #pragma unroll
            for (int q = 0; q < 4; ++q) {
                const int i = c + 16 * q;
                const int partner = i ^ j;
                if (partner > i) {
                    const unsigned a = skey[node][i];
                    const unsigned b = skey[node][partner];
                    const bool asc = (i & kk) == 0;
                    if ((a > b) == asc) {
                        skey[node][i]       = b;
                        skey[node][partner] = a;
                    }
                }
            }
            __syncthreads();
        }
    }

    // ---- phase 1: sorted 4-deep gather batches, fma with pw[l] ----
    float a0 = 0.f, a1 = 0.f, a2 = 0.f, a3 = 0.f,
          a4 = 0.f, a5 = 0.f, a6 = 0.f, a7 = 0.f;
    #pragma unroll 2
    for (int g = 0; g < 64; g += 4) {
        const unsigned k0_ = skey[node][g + 0];   // same addr across node's
        const unsigned k1_ = skey[node][g + 1];   // 16 lanes -> LDS broadcast
        const unsigned k2_ = skey[node][g + 2];
        const unsigned k3_ = skey[node][g + 3];
        uint4 hv0 = feats_h4[(size_t)(k0_ >> 3) * 16 + c];
        uint4 hv1 = feats_h4[(size_t)(k1_ >> 3) * 16 + c];
        uint4 hv2 = feats_h4[(size_t)(k2_ >> 3) * 16 + c];
        uint4 hv3 = feats_h4[(size_t)(k3_ >> 3) * 16 + c];
        #define ACCW(hv, key)                                                           \
        {                                                                               \
            const int l = (int)((key) & 7u);                                            \
            const float4 w0 = spw4[l * 32 + 2 * c];                                     \
            const float4 w1 = spw4[l * 32 + 2 * c + 1];                                 \
            const float2 f0 = __half22float2(*reinterpret_cast<const __half2*>(&hv.x)); \
            const float2 f1 = __half22float2(*reinterpret_cast<const __half2*>(&hv.y)); \
            const float2 f2 = __half22float2(*reinterpret_cast<const __half2*>(&hv.z)); \
            const float2 f3 = __half22float2(*reinterpret_cast<const __half2*>(&hv.w)); \
            a0 = fmaf(f0.x, w0.x, a0); a1 = fmaf(f0.y, w0.y, a1);                       \
            a2 = fmaf(f1.x, w0.z, a2); a3 = fmaf(f1.y, w0.w, a3);                       \
            a4 = fmaf(f2.x, w1.x, a4); a5 = fmaf(f2.y, w1.y, a5);                       \
            a6 = fmaf(f3.x, w1.z, a6); a7 = fmaf(f3.y, w1.w, a7);                       \
        }
        ACCW(hv0, k0_) ACCW(hv1, k1_) ACCW(hv2, k2_) ACCW(hv3, k3_)
        #undef ACCW
    }
    {
        float4 r0, r1;
        r0.x = a0 * 0.125f; r0.y = a1 * 0.125f; r0.z = a2 * 0.125f; r0.w = a3 * 0.125f;
        r1.x = a4 * 0.125f; r1.y = a5 * 0.125f; r1.z = a6 * 0.125f; r1.w = a7 * 0.125f;
        sres4[node][2 * c]     = r0;
        sres4[node][2 * c + 1] = r1;
    }

    // ---- phase 2: out[node][j], j = c + 16*jj, register array o[8] ----
    float o[8] = {0.f, 0.f, 0.f, 0.f, 0.f, 0.f, 0.f, 0.f};

    #pragma unroll
    for (int kt = 0; kt < HIDDEN / KT; ++kt) {
        __syncthreads();   // protect fcwt reuse (and sres on first iter)
        {
            const int j    = tid >> 1;        // 0..127
            const int half = tid & 1;         // 0..1
            const int gbase = j * 32 + kt * (KT / 4) + half * 4;
            const int lbase = half * 16;
            #pragma unroll
            for (int q = 0; q < 4; ++q) {
                const float4 v = fcw4[gbase + q];
                fcwt[j][lbase + q * 4 + 0] = v.x;
                fcwt[j][lbase + q * 4 + 1] = v.y;
                fcwt[j][lbase + q * 4 + 2] = v.z;
                fcwt[j][lbase + q * 4 + 3] = v.w;
            }
        }
        __syncthreads();

        #pragma unroll
        for (int kc = 0; kc < KT / 4; ++kc) {
            const float4 rv = sres4[node][kt * (KT / 4) + kc];  // 16-lane broadcast
            const int k0 = kc * 4;
            #pragma unroll
            for (int jj = 0; jj < 8; ++jj) {
                const int j = c + 16 * jj;
                o[jj] = fmaf(rv.x, fcwt[j][k0    ], o[jj]);
                o[jj] = fmaf(rv.y, fcwt[j][k0 + 1], o[jj]);
                o[jj] = fmaf(rv.z, fcwt[j][k0 + 2], o[jj]);
                o[jj] = fmaf(rv.w, fcwt[j][k0 + 3], o[jj]);
            }
        }
    }

    // ReLU + store: per jj, 16 consecutive floats per node (64B runs)
    {
        const size_t obase = (size_t)(n0 + node) * HIDDEN + c;
        #pragma unroll
        for (int jj = 0; jj < 8; ++jj) {
            const float v = o[jj] > 0.f ? o[jj] : 0.f;
            out[obase + 16 * jj] = v;
        }
    }
}

// ---------------- Fallback: R0's fused f32 kernel (proven, no ws needed) ----------------
__global__ void PathGCNLayer_61306363183203_fused(
    const float4* __restrict__ feats4,
    const int*    __restrict__ paths,
    const float4* __restrict__ pw4,
    const float4* __restrict__ fcw4,
    float*        __restrict__ out)
{
    __shared__ int    sidx[NPATH * 8 * PLEN];
    __shared__ float4 sres4[8][33];
    __shared__ float  fcwt[HIDDEN][KT + 1];

    const int tid  = threadIdx.x;
    const int n0   = blockIdx.x * 8;
    const int node = tid >> 5;
    const int c    = tid & 31;

    {
        const int p = tid >> 5;
        const int i = tid & 31;
        const size_t base = (size_t)p * (N_NODES * PLEN) + (size_t)n0 * PLEN;
        sidx[p * 64 + i]      = paths[base + i];
        sidx[p * 64 + i + 32] = paths[base + i + 32];
    }
    __syncthreads();

    float ax = 0.0f, ay = 0.0f, az = 0.0f, aw = 0.0f;
    #pragma unroll
    for (int l = 0; l < PLEN; ++l) {
        float sx = 0.0f, sy = 0.0f, sz = 0.0f, sw = 0.0f;
        #pragma unroll
        for (int p = 0; p < NPATH; ++p) {
            const int idx = sidx[p * 64 + node * PLEN + l];
            const float4 v = feats4[(size_t)idx * 32 + c];
            sx += v.x; sy += v.y; sz += v.z; sw += v.w;
        }
        const float4 w = pw4[l * 32 + c];
        ax = fmaf(sx, w.x, ax);
        ay = fmaf(sy, w.y, ay);
        az = fmaf(sz, w.z, az);
        aw = fmaf(sw, w.w, aw);
    }
    {
        float4 r;
        r.x = ax * 0.125f; r.y = ay * 0.125f;
        r.z = az * 0.125f; r.w = aw * 0.125f;
        sres4[node][c] = r;
    }

    float o0 = 0.0f, o1 = 0.0f, o2 = 0.0f, o3 = 0.0f;
    #pragma unroll
    for (int kt = 0; kt < HIDDEN / KT; ++kt) {
        __syncthreads();
        {
            const int j    = tid >> 1;
            const int half = tid & 1;
            const int gbase = j * 32 + kt * (KT / 4) + half * 4;
            const int lbase = half * 16;
            #pragma unroll
            for (int q = 0; q < 4; ++q) {
                const float4 v = fcw4[gbase + q];
                fcwt[j][lbase + q * 4 + 0] = v.x;
                fcwt[j][lbase + q * 4 + 1] = v.y;
                fcwt[j][lbase + q * 4 + 2] = v.z;
                fcwt[j][lbase + q * 4 + 3] = v.w;
            }
        }
        __syncthreads();
        #pragma unroll
        for (int kc = 0; kc < KT / 4; ++kc) {
            const float4 rv = sres4[node][kt * (KT / 4) + kc];
            const int k0 = kc * 4;
            o0 = fmaf(rv.x, fcwt[c      ][k0    ], o0);
            o1 = fmaf(rv.x, fcwt[c + 32 ][k0    ], o1);
            o2 = fmaf(rv.x, fcwt[c + 64 ][k0    ], o2);
            o3 = fmaf(rv.x, fcwt[c + 96 ][k0    ], o3);
            o0 = fmaf(rv.y, fcwt[c      ][k0 + 1], o0);
            o1 = fmaf(rv.y, fcwt[c + 32 ][k0 + 1], o1);
            o2 = fmaf(rv.y, fcwt[c + 64 ][k0 + 1], o2);
            o3 = fmaf(rv.y, fcwt[c + 96 ][k0 + 1], o3);
            o0 = fmaf(rv.z, fcwt[c      ][k0 + 2], o0);
            o1 = fmaf(rv.z, fcwt[c + 32 ][k0 + 2], o1);
            o2 = fmaf(rv.z, fcwt[c + 64 ][k0 + 2], o2);
            o3 = fmaf(rv.z, fcwt[c + 96 ][k0 + 2], o3);
            o0 = fmaf(rv.w, fcwt[c      ][k0 + 3], o0);
            o1 = fmaf(rv.w, fcwt[c + 32 ][k0 + 3], o1);
            o2 = fmaf(rv.w, fcwt[c + 64 ][k0 + 3], o2);
            o3 = fmaf(rv.w, fcwt[c + 96 ][k0 + 3], o3);
        }
    }
    {
        const size_t obase = (size_t)(n0 + node) * HIDDEN + c;
        out[obase]      = o0 > 0.0f ? o0 : 0.0f;
        out[obase + 32] = o1 > 0.0f ? o1 : 0.0f;
        out[obase + 64] = o2 > 0.0f ? o2 : 0.0f;
        out[obase + 96] = o3 > 0.0f ? o3 : 0.0f;
    }
}

extern "C" void kernel_launch(void* const* d_in, const int* in_sizes, int n_in,
                              void* d_out, int out_size, void* d_ws, size_t ws_size,
                              hipStream_t stream) {
    const float4* feats4 = (const float4*)d_in[0];  // (N,128) f32
    const int*    paths  = (const int*)d_in[1];     // (8,N,8) int32
    // d_in[2] = init_feats — unused by the reference
    const float4* pw4    = (const float4*)d_in[3];  // (1,8,128) f32
    const float4* fcw4   = (const float4*)d_in[4];  // (128,128) f32
    float* out = (float*)d_out;
    (void)in_sizes; (void)n_in; (void)out_size;

    const size_t half_bytes = (size_t)N_NODES * HIDDEN * sizeof(unsigned short); // 25.6 MB
    if (d_ws != nullptr && ws_size >= half_bytes) {
        uint2* fh = (uint2*)d_ws;
        const int cvt_blocks = (N_NODES * 32 + 255) / 256;   // 3.2M float4s
        PathGCNLayer_61306363183203_tohalf<<<cvt_blocks, 256, 0, stream>>>(feats4, fh);
        PathGCNLayer_61306363183203_fused_hs<<<N_NODES / NPB, 256, 0, stream>>>(
            (const uint4*)d_ws, paths, pw4, fcw4, out);
    } else {
        PathGCNLayer_61306363183203_fused<<<N_NODES / 8, 256, 0, stream>>>(
            feats4, paths, pw4, fcw4, out);
    }
}